// Round 11
// baseline (270.340 us; speedup 1.0000x reference)
//
#include <hip/hip_runtime.h>
#include <math.h>

#define B 1024
#define M 15
#define H 256
#define E 256
#define V 30000
#define U 1000

typedef float  vf4    __attribute__((ext_vector_type(4)));
typedef __bf16 bf16x8 __attribute__((ext_vector_type(8)));
typedef float  f32x4  __attribute__((ext_vector_type(4)));

// output layout (flat f32 concat, reference return order)
#define O_OUT   0
#define O_HID   ((size_t)B*V)
#define O_EMB   (O_HID + (size_t)B*H)
#define O_GRU   (O_EMB + (size_t)B*E)
#define O_ATT   (O_GRU + (size_t)B*H)

#define GLDS(g, l) __builtin_amdgcn_global_load_lds( \
    (const __attribute__((address_space(1))) void*)(g), \
    (__attribute__((address_space(3))) void*)(l), 16, 0, 0)

union BF8 { __bf16 h[8]; bf16x8 v; };
union BF4 { __bf16 h[4]; unsigned long long u; };

// =============== kernel1: sort (bid 0) | transpose (1..500) | wcat (501..564) ===============
#define K1_TR   500
#define K1_WC   64
#define K1_TOT  (1 + K1_TR + K1_WC)

__global__ __launch_bounds__(1024) void pre_kernel(
    const int*   __restrict__ ul,
    const float* __restrict__ Wih,          // (3H,2E)
    const float* __restrict__ Whh,          // (3H,H)
    const float* __restrict__ lin_W,        // (H,V)
    int* __restrict__ order, int* __restrict__ rbase_g,
    __bf16* __restrict__ wcat,              // (1024,768), gate-group-reordered
    __bf16* __restrict__ WT)                // (V,H)
{
    __shared__ __align__(16) char smem[32640];
    const int bid = blockIdx.x;
    const int tid = threadIdx.x;

    if (bid == 0) {
        // ---------------- counting sort by user ----------------
        __shared__ int cnt[1024];
        __shared__ int base[1024];
        cnt[tid] = 0;
        __syncthreads();
        const int u = ul[tid];
        atomicAdd(&cnt[u], 1);
        __syncthreads();
        int c0 = cnt[tid];
        int v  = c0;
        for (int off = 1; off < 1024; off <<= 1) {
            int add = (tid >= off) ? cnt[tid - off] : 0;
            __syncthreads();
            v += add;
            cnt[tid] = v;
            __syncthreads();
        }
        base[tid]    = v - c0;
        rbase_g[tid] = v - c0;
        __syncthreads();
        int pos = atomicAdd(&base[u], 1);
        order[pos] = tid;
        return;
    }

    if (bid <= K1_TR) {
        // ---------------- transpose: lin_W (H,V) f32 -> WT (V,H) bf16 ----------------
        const int t   = bid - 1;
        const int v0  = (t % 125) * 240;
        const int k0  = (t / 125) * 64;
        const int lane = tid & 63, kq = tid >> 6;   // kq 0..15
        __bf16* T = (__bf16*)smem;                  // 240*68 bf16 = 32640 B

        if (lane < 60) {
            int kr = kq * 4;
            vf4 f0 = *(const vf4*)&lin_W[(size_t)(k0 + kr + 0) * V + v0 + lane * 4];
            vf4 f1 = *(const vf4*)&lin_W[(size_t)(k0 + kr + 1) * V + v0 + lane * 4];
            vf4 f2 = *(const vf4*)&lin_W[(size_t)(k0 + kr + 2) * V + v0 + lane * 4];
            vf4 f3 = *(const vf4*)&lin_W[(size_t)(k0 + kr + 3) * V + v0 + lane * 4];
            #pragma unroll
            for (int j = 0; j < 4; ++j) {
                BF4 pk;
                pk.h[0] = (__bf16)f0[j];
                pk.h[1] = (__bf16)f1[j];
                pk.h[2] = (__bf16)f2[j];
                pk.h[3] = (__bf16)f3[j];
                int v = lane * 4 + j;
                *(unsigned long long*)&T[v * 68 + kr] = pk.u;
            }
        }
        __syncthreads();
        #pragma unroll
        for (int r = 0; r < 4; ++r) {
            int L = r * 1024 + tid;
            int v = L >> 4, c = L & 15;
            if (v < 240)
                __builtin_nontemporal_store(
                    *(const unsigned long long*)&T[v * 68 + c * 4],
                    (unsigned long long*)&WT[(size_t)(v0 + v) * H + k0 + c * 4]);
        }
        return;
    }

    // ---------------- wcat (gate-group column order) ----------------
    {
        const int wb   = bid - 1 - K1_TR;
        const int lane = tid & 63;
        const int n    = wb * 16 + (tid >> 6);
        const int r    = (n >> 2) + ((n & 3) << 8);
        #pragma unroll
        for (int i = 0; i < 3; ++i) {
            int k = i * 256 + lane * 4;
            vf4 v = {0.f, 0.f, 0.f, 0.f};
            if (r < 512) {
                v = (k < 512) ? *(const vf4*)&Wih[(size_t)r * 512 + k]
                              : *(const vf4*)&Whh[(size_t)r * 256 + (k - 512)];
            } else if (r < 768) {
                if (k < 512) v = *(const vf4*)&Wih[(size_t)r * 512 + k];
            } else {
                if (k >= 512) v = *(const vf4*)&Whh[(size_t)(r - 256) * 256 + (k - 512)];
            }
            BF4 p;
            p.h[0]=(__bf16)v[0]; p.h[1]=(__bf16)v[1]; p.h[2]=(__bf16)v[2]; p.h[3]=(__bf16)v[3];
            *(unsigned long long*)&wcat[(size_t)n * 768 + k] = p.u;
        }
    }
}

// ---------------- Stage A: per-user attention (MFMA, reg-B, paired) ----------------
__global__ __launch_bounds__(256, 3) void attn_kernel(
    const float* __restrict__ hidden,       // (1,B,H)
    const float* __restrict__ inter_output, // (B,M,H)
    const int*   __restrict__ user_list,    // (B,)
    const int*   __restrict__ order,        // (B,)
    const int*   __restrict__ rbase,        // (1024,)
    const float* __restrict__ inter_W,      // (U,H,H)
    const float* __restrict__ inter_b,      // (U,H)
    const float* __restrict__ hidden_W,     // (U,H,H)
    const float* __restrict__ hidden_b,     // (U,H)
    const float* __restrict__ lt1_W,        // (U,2H,H)
    const float* __restrict__ lt1_b,        // (U,H)
    const float* __restrict__ scale_W,      // (U,H)
    const float* __restrict__ scale_b,      // (U,)
    const float* __restrict__ emb,          // (B,1,E)
    float* __restrict__ out,
    __bf16* __restrict__ xcat)              // (B,768)
{
    __shared__ __align__(16) char smem[34432];
    const int bid = blockIdx.x;
    const int tid = threadIdx.x;

    const int s   = ((bid & 7) << 7) + (bid >> 3);  // XCD chunk swizzle
    const int b0  = order[s];
    const int u   = user_list[b0];

    // cvt_xh for this block's sample (all 1024 blocks)
    {
        float ev = emb[(size_t)b0 * E + tid];
        float hv = hidden[(size_t)b0 * H + tid];
        xcat[(size_t)b0 * 768 + tid]       = (__bf16)ev;
        xcat[(size_t)b0 * 768 + 512 + tid] = (__bf16)hv;
        __builtin_nontemporal_store(ev, &out[O_EMB + (size_t)b0 * E + tid]);
    }

    if ((s - rbase[u]) & 1) return;         // not a run head
    bool paired = false;
    int  b1 = b0;
    if (s + 1 < B) {
        int ob = order[s + 1];
        if (user_list[ob] == u) { paired = true; b1 = ob; }
    }

    const int lane = tid & 63;
    const int wave = tid >> 6;
    const int wn0  = wave * 64;

    __bf16* Abuf = (__bf16*)smem;                       // 32 KB
    __bf16* hta  = (__bf16*)(smem + 32768);             // 2*256 bf16 = 1 KB
    float*  red  = (float*)(smem + 32768 + 1024);       // 2*64 f32 = 512 B
    float*  e_lds= (float*)(smem + 32768 + 1024 + 512); // 2*16 f32 = 128 B

    // ---- phase 1: A = [io|0 ; 0|ht] for both samples ----
    {
        const int r    = tid >> 3;
        const int part = tid & 7;
        const int sm   = r >> 4;
        const int mr   = r & 15;
        const int bs   = sm ? b1 : b0;
        const bool zr  = (sm == 1) && !paired;
        #pragma unroll
        for (int it = 0; it < 8; ++it) {
            int c = part + it * 8;
            int k = c * 8;
            BF8 p;
            #pragma unroll
            for (int j = 0; j < 8; ++j) p.h[j] = (__bf16)0.f;
            if (!zr) {
                if (mr < 15 && k < 256) {
                    vf4 f0 = *(const vf4*)&inter_output[(size_t)bs * M * H + mr * H + k];
                    vf4 f1 = *(const vf4*)&inter_output[(size_t)bs * M * H + mr * H + k + 4];
                    p.h[0]=(__bf16)f0[0]; p.h[1]=(__bf16)f0[1]; p.h[2]=(__bf16)f0[2]; p.h[3]=(__bf16)f0[3];
                    p.h[4]=(__bf16)f1[0]; p.h[5]=(__bf16)f1[1]; p.h[6]=(__bf16)f1[2]; p.h[7]=(__bf16)f1[3];
                } else if (mr == 15 && k >= 256) {
                    vf4 f0 = *(const vf4*)&hidden[(size_t)bs * H + (k - 256)];
                    vf4 f1 = *(const vf4*)&hidden[(size_t)bs * H + (k - 256) + 4];
                    p.h[0]=(__bf16)f0[0]; p.h[1]=(__bf16)f0[1]; p.h[2]=(__bf16)f0[2]; p.h[3]=(__bf16)f0[3];
                    p.h[4]=(__bf16)f1[0]; p.h[5]=(__bf16)f1[1]; p.h[6]=(__bf16)f1[2]; p.h[7]=(__bf16)f1[3];
                }
            }
            *(bf16x8*)&Abuf[r * 512 + (c ^ (r & 7)) * 8] = p.v;
        }
    }
    __syncthreads();

    const float* Wi_base  = inter_W  + (size_t)u * H * H;
    const float* Wh_base  = hidden_W + (size_t)u * H * H;
    const float* lt1_base = lt1_W    + (size_t)u * 2 * H * H;

    const int ocol = wn0 + (lane & 15);
    const int krow = (lane >> 4) * 8;

    f32x4 acc1[2][4];
    #pragma unroll
    for (int mf = 0; mf < 2; ++mf)
        #pragma unroll
        for (int nf = 0; nf < 4; ++nf) { f32x4 z = {0.f,0.f,0.f,0.f}; acc1[mf][nf] = z; }

    // ================= GEMM 1 =================
    #pragma unroll 2
    for (int ks = 0; ks < 16; ++ks) {
        const float* Bp = ((ks < 8) ? (Wi_base + (size_t)(ks * 32) * H)
                                    : (Wh_base + (size_t)((ks - 8) * 32) * H))
                          + (size_t)krow * H + ocol;
        float t[4][8];
        #pragma unroll
        for (int j = 0; j < 8; ++j)
            #pragma unroll
            for (int nf = 0; nf < 4; ++nf)
                t[nf][j] = Bp[(size_t)j * H + nf * 16];
        bf16x8 bfr[4];
        #pragma unroll
        for (int nf = 0; nf < 4; ++nf) {
            BF8 pk;
            #pragma unroll
            for (int j = 0; j < 8; ++j) pk.h[j] = (__bf16)t[nf][j];
            bfr[nf] = pk.v;
        }
        int sca = ((ks * 4 + (lane >> 4)) ^ (lane & 7)) * 8;
        bf16x8 a0 = *(const bf16x8*)&Abuf[(lane & 15) * 512 + sca];
        #pragma unroll
        for (int nf = 0; nf < 4; ++nf)
            acc1[0][nf] = __builtin_amdgcn_mfma_f32_16x16x32_bf16(a0, bfr[nf], acc1[0][nf], 0, 0, 0);
        if (paired) {
            bf16x8 a1 = *(const bf16x8*)&Abuf[(16 + (lane & 15)) * 512 + sca];
            #pragma unroll
            for (int nf = 0; nf < 4; ++nf)
                acc1[1][nf] = __builtin_amdgcn_mfma_f32_16x16x32_bf16(a1, bfr[nf], acc1[1][nf], 0, 0, 0);
        }
    }
    __syncthreads();

    // ---- extract ht_a + hidden_b ; io_a+bi into Abuf k>=256 ----
    if ((lane >> 4) == 3) {
        #pragma unroll
        for (int nf = 0; nf < 4; ++nf) {
            int o = wn0 + nf * 16 + (lane & 15);
            float hb = hidden_b[(size_t)u * H + o];
            hta[o]       = (__bf16)(acc1[0][nf][3] + hb);
            hta[256 + o] = (__bf16)(acc1[1][nf][3] + hb);
        }
    }
    #pragma unroll
    for (int mf = 0; mf < 2; ++mf) {
        #pragma unroll
        for (int nf = 0; nf < 4; ++nf) {
            int o  = wn0 + nf * 16 + (lane & 15);
            float bi = inter_b[(size_t)u * H + o];
            int k  = 256 + o;
            #pragma unroll
            for (int j = 0; j < 4; ++j) {
                int r  = mf * 16 + (lane >> 4) * 4 + j;
                Abuf[r * 512 + ((k >> 3) ^ (r & 7)) * 8 + (k & 7)] = (__bf16)(acc1[mf][nf][j] + bi);
            }
        }
    }
    __syncthreads();

    // ---- phase 2 low-K: hta broadcast ----
    {
        const int r    = tid >> 3;
        const int part = tid & 7;
        const int sm   = r >> 4;
        #pragma unroll
        for (int it = 0; it < 4; ++it) {
            int c = part + it * 8;
            bf16x8 hv = *(const bf16x8*)&hta[sm * 256 + c * 8];
            *(bf16x8*)&Abuf[r * 512 + (c ^ (r & 7)) * 8] = hv;
        }
    }
    __syncthreads();

    f32x4 acc2[2][4];
    #pragma unroll
    for (int mf = 0; mf < 2; ++mf)
        #pragma unroll
        for (int nf = 0; nf < 4; ++nf) { f32x4 z = {0.f,0.f,0.f,0.f}; acc2[mf][nf] = z; }

    // ================= GEMM 2 =================
    #pragma unroll 2
    for (int ks = 0; ks < 16; ++ks) {
        const float* Bp = lt1_base + (size_t)(ks * 32) * H + (size_t)krow * H + ocol;
        float t[4][8];
        #pragma unroll
        for (int j = 0; j < 8; ++j)
            #pragma unroll
            for (int nf = 0; nf < 4; ++nf)
                t[nf][j] = Bp[(size_t)j * H + nf * 16];
        bf16x8 bfr[4];
        #pragma unroll
        for (int nf = 0; nf < 4; ++nf) {
            BF8 pk;
            #pragma unroll
            for (int j = 0; j < 8; ++j) pk.h[j] = (__bf16)t[nf][j];
            bfr[nf] = pk.v;
        }
        int sca = ((ks * 4 + (lane >> 4)) ^ (lane & 7)) * 8;
        bf16x8 a0 = *(const bf16x8*)&Abuf[(lane & 15) * 512 + sca];
        #pragma unroll
        for (int nf = 0; nf < 4; ++nf)
            acc2[0][nf] = __builtin_amdgcn_mfma_f32_16x16x32_bf16(a0, bfr[nf], acc2[0][nf], 0, 0, 0);
        if (paired) {
            bf16x8 a1 = *(const bf16x8*)&Abuf[(16 + (lane & 15)) * 512 + sca];
            #pragma unroll
            for (int nf = 0; nf < 4; ++nf)
                acc2[1][nf] = __builtin_amdgcn_mfma_f32_16x16x32_bf16(a1, bfr[nf], acc2[1][nf], 0, 0, 0);
        }
    }

    // ---- energies ----
    float p0[4] = {0.f,0.f,0.f,0.f};
    float p1[4] = {0.f,0.f,0.f,0.f};
    #pragma unroll
    for (int nf = 0; nf < 4; ++nf) {
        int o = wn0 + nf * 16 + (lane & 15);
        float l1b = lt1_b[(size_t)u * H + o];
        float sw  = scale_W[(size_t)u * H + o];
        #pragma unroll
        for (int j = 0; j < 4; ++j)
            p0[j] += tanhf(acc2[0][nf][j] + l1b) * sw;
        if (paired)
            #pragma unroll
            for (int j = 0; j < 4; ++j)
                p1[j] += tanhf(acc2[1][nf][j] + l1b) * sw;
    }
    #pragma unroll
    for (int j = 0; j < 4; ++j) {
        float v = p0[j];
        v += __shfl_xor(v, 1, 64); v += __shfl_xor(v, 2, 64);
        v += __shfl_xor(v, 4, 64); v += __shfl_xor(v, 8, 64);
        if ((lane & 15) == 0) red[0 * 64 + wave * 16 + (lane >> 4) * 4 + j] = v;
        float w = p1[j];
        w += __shfl_xor(w, 1, 64); w += __shfl_xor(w, 2, 64);
        w += __shfl_xor(w, 4, 64); w += __shfl_xor(w, 8, 64);
        if ((lane & 15) == 0) red[1 * 64 + wave * 16 + (lane >> 4) * 4 + j] = w;
    }
    __syncthreads();
    if (tid < 32) {
        int sm = tid >> 4, mm = tid & 15;
        e_lds[sm * 16 + mm] = red[sm * 64 + mm] + red[sm * 64 + 16 + mm]
                            + red[sm * 64 + 32 + mm] + red[sm * 64 + 48 + mm]
                            + scale_b[u];
    }
    __syncthreads();

    const int nsm = paired ? 2 : 1;
    for (int sm = 0; sm < nsm; ++sm) {
        const int bs = sm ? b1 : b0;
        float mx = -1e30f;
        #pragma unroll
        for (int m = 0; m < M; ++m) mx = fmaxf(mx, e_lds[sm * 16 + m]);
        float sum = 0.f;
        float aw[M];
        #pragma unroll
        for (int m = 0; m < M; ++m) { aw[m] = expf(e_lds[sm * 16 + m] - mx); sum += aw[m]; }
        float inv = 1.f / sum;
        if (tid < M)
            __builtin_nontemporal_store(aw[tid] * inv, &out[O_ATT + (size_t)bs * M + tid]);
        float ctx = 0.f;
        #pragma unroll
        for (int m = 0; m < M; ++m)
            ctx += aw[m] * inter_output[(size_t)bs * M * H + m * H + tid];
        xcat[(size_t)bs * 768 + 256 + tid] = (__bf16)(ctx * inv);
    }
}

// ---- fused GRU GEMM + gate: gates tile in LDS, hn written directly ----
__global__ __launch_bounds__(256) void xgemm_gate_kernel(
    const __bf16* __restrict__ xcat, const __bf16* __restrict__ wcat,
    const float* __restrict__ hidden,
    const float* __restrict__ bih, const float* __restrict__ bhh,
    float* __restrict__ out, __bf16* __restrict__ hnb)
{
    const int n0   = blockIdx.x * 64;
    const int m0   = blockIdx.y * 64;
    const int tid  = threadIdx.x;
    const int wave = tid >> 6, lane = tid & 63;
    const int wm   = wave >> 1, wn = wave & 1;

    __shared__ __align__(16) __bf16 Al[64 * 128];
    __shared__ __align__(16) __bf16 Bl[64 * 128];
    __shared__ __align__(16) float  Cs[64 * 68];

    f32x4 acc[2][2];
    #pragma unroll
    for (int mf = 0; mf < 2; ++mf)
        #pragma unroll
        for (int nf = 0; nf < 2; ++nf) { f32x4 z = {0.f,0.f,0.f,0.f}; acc[mf][nf] = z; }

    for (int ks = 0; ks < 6; ++ks) {
        #pragma unroll
        for (int r = 0; r < 4; ++r) {
            int L = r * 256 + tid;
            int row = L >> 4, c = L & 15;
            int sc = c ^ (row & 7);
            GLDS(xcat + (size_t)(m0 + row) * 768 + ks * 128 + sc * 8, &Al[(size_t)L * 8]);
        }
        #pragma unroll
        for (int r = 0; r < 4; ++r) {
            int L = r * 256 + tid;
            int row = L >> 4, c = L & 15;
            int sc = c ^ (row & 7);
            GLDS(wcat + (size_t)(n0 + row) * 768 + ks * 128 + sc * 8, &Bl[(size_t)L * 8]);
        }
        __syncthreads();
        #pragma unroll
        for (int kk = 0; kk < 4; ++kk) {
            bf16x8 af[2];
            #pragma unroll
            for (int mf = 0; mf < 2; ++mf) {
                int row = wm * 32 + mf * 16 + (lane & 15);
                int c   = kk * 4 + (lane >> 4);
                af[mf] = *(const bf16x8*)&Al[row * 128 + (c ^ (row & 7)) * 8];
            }
            bf16x8 bfr[2];
            #pragma unroll
            for (int nf = 0; nf < 2; ++nf) {
                int col = wn * 32 + nf * 16 + (lane & 15);
                int c   = kk * 4 + (lane >> 4);
                bfr[nf] = *(const bf16x8*)&Bl[col * 128 + (c ^ (col & 7)) * 8];
            }
            #pragma unroll
            for (int mf = 0; mf < 2; ++mf)
                #pragma unroll
                for (int nf = 0; nf < 2; ++nf)
                    acc[mf][nf] = __builtin_amdgcn_mfma_f32_16x16x32_bf16(
                        af[mf], bfr[nf], acc[mf][nf], 0, 0, 0);
        }
        __syncthreads();
    }

    #pragma unroll
    for (int nf = 0; nf < 2; ++nf) {
        int lc = wn * 32 + nf * 16 + (lane & 15);
        #pragma unroll
        for (int mf = 0; mf < 2; ++mf) {
            int lr = wm * 32 + mf * 16 + (lane >> 4) * 4;
            f32x4 a = acc[mf][nf];
            #pragma unroll
            for (int j = 0; j < 4; ++j)
                Cs[(lr + j) * 68 + lc] = a[j];
        }
    }
    __syncthreads();

    #pragma unroll
    for (int k = 0; k < 4; ++k) {
        int idx = k * 256 + tid;
        int r = idx >> 4, g = idx & 15;
        f32x4 c = *(const f32x4*)&Cs[r * 68 + g * 4];
        int b = m0 + r;
        int j = (n0 >> 2) + g;
        float rs  = c[0] + bih[j]       + bhh[j];
        float zs  = c[1] + bih[256 + j] + bhh[256 + j];
        float gin = c[2] + bih[512 + j];
        float ghn = c[3] + bhh[512 + j];
        float h   = hidden[(size_t)b * H + j];
        float r_  = 1.f / (1.f + expf(-rs));
        float z_  = 1.f / (1.f + expf(-zs));
        float n_  = tanhf(gin + r_ * ghn);
        float hn  = (1.f - z_) * n_ + z_ * h;
        __builtin_nontemporal_store(hn, &out[O_HID + (size_t)b * H + j]);
        __builtin_nontemporal_store(hn, &out[O_GRU + (size_t)b * H + j]);
        hnb[(size_t)b * H + j] = (__bf16)hn;
    }
}

// -------- Stage C (MFMA): out = hnew(bf16) @ WT^T + lin_b --------
// Register-direct operands (no LDS staging, no K-loop barriers): A/B fragments
// are contiguous 16B runs along K in hnb/WT. LDS used only for C-transpose.
#define GBM 64
#define GBN 128
#define NTM 16
#define NTN 235
#define NWG (NTN * NTM)
__global__ __launch_bounds__(256, 4) void out_mfma_kernel(
    const __bf16* __restrict__ hnb,
    const __bf16* __restrict__ WT,
    const float* __restrict__ lin_b,
    float* __restrict__ out)
{
    const int L  = blockIdx.x;
    const int s  = (L & 7) * (NWG / 8) + (L >> 3);
    const int nt = s >> 4, mt = s & 15;
    const int n0 = nt * GBN;
    const int m0 = mt * GBM;
    const int tid  = threadIdx.x;
    const int wave = tid >> 6, lane = tid & 63;
    const int wn0  = wave * 32;

    __shared__ __align__(16) float Cs[GBM * GBN];   // 32 KB (C transpose only)

    f32x4 acc[4][2];
    #pragma unroll
    for (int mf = 0; mf < 4; ++mf)
        #pragma unroll
        for (int nf = 0; nf < 2; ++nf) {
            f32x4 z = {0.f, 0.f, 0.f, 0.f};
            acc[mf][nf] = z;
        }

    // per-lane base addresses
    const int arow = lane & 15;               // A row within 16-row fragment
    const int kofs = (lane >> 4) * 8;         // k sub-offset within K=32 step
    const __bf16* Abase = hnb + (size_t)(m0 + arow) * H + kofs;
    int bcol0 = n0 + wn0 + (lane & 15);       // B col for nf=0
    int bcol1 = bcol0 + 16;
    if (bcol0 >= V) bcol0 = V - 1;
    if (bcol1 >= V) bcol1 = V - 1;
    const __bf16* Bbase0 = WT + (size_t)bcol0 * H + kofs;
    const __bf16* Bbase1 = WT + (size_t)bcol1 * H + kofs;

    // K loop: 8 steps of K=32, no barriers — compiler pipelines loads freely
    #pragma unroll
    for (int ks = 0; ks < 8; ++ks) {
        const int k = ks * 32;
        bf16x8 af[4];
        #pragma unroll
        for (int mf = 0; mf < 4; ++mf)
            af[mf] = *(const bf16x8*)(Abase + (size_t)(mf * 16) * H + k);
        bf16x8 b0 = *(const bf16x8*)(Bbase0 + k);
        bf16x8 b1 = *(const bf16x8*)(Bbase1 + k);
        #pragma unroll
        for (int mf = 0; mf < 4; ++mf) {
            acc[mf][0] = __builtin_amdgcn_mfma_f32_16x16x32_bf16(af[mf], b0, acc[mf][0], 0, 0, 0);
            acc[mf][1] = __builtin_amdgcn_mfma_f32_16x16x32_bf16(af[mf], b1, acc[mf][1], 0, 0, 0);
        }
    }

    // ---- epilogue: stage C tile (64x128 f32 = 32 KB) in LDS, coalesced nt row writes ----
    #pragma unroll
    for (int nf = 0; nf < 2; ++nf) {
        int col = wn0 + nf * 16 + (lane & 15);
        #pragma unroll
        for (int mf = 0; mf < 4; ++mf) {
            #pragma unroll
            for (int j = 0; j < 4; ++j)
                Cs[(mf * 16 + (lane >> 4) * 4 + j) * 128 + col] = acc[mf][nf][j];
        }
    }
    __syncthreads();

    const int c4 = tid & 31;
    const bool nok = (n0 + c4 * 4 + 3 < V);
    f32x4 lb = {0.f, 0.f, 0.f, 0.f};
    if (nok) lb = *(const f32x4*)&lin_b[n0 + c4 * 4];
    #pragma unroll
    for (int it = 0; it < 8; ++it) {
        int idx = it * 256 + tid;
        int r = idx >> 5;
        f32x4 c = *(const f32x4*)&Cs[r * 128 + c4 * 4];
        c += lb;
        if (nok)
            __builtin_nontemporal_store(c, (f32x4*)&out[(size_t)(m0 + r) * V + n0 + c4 * 4]);
    }
}

extern "C" void kernel_launch(void* const* d_in, const int* in_sizes, int n_in,
                              void* d_out, int out_size, void* d_ws, size_t ws_size,
                              hipStream_t stream) {
    const float* emb    = (const float*)d_in[1];
    const float* hidden = (const float*)d_in[2];
    const float* io     = (const float*)d_in[3];
    const int*   ul     = (const int*)  d_in[4];
    const float* iW     = (const float*)d_in[5];
    const float* ib     = (const float*)d_in[6];
    const float* hW     = (const float*)d_in[7];
    const float* hb     = (const float*)d_in[8];
    const float* l1W    = (const float*)d_in[9];
    const float* l1b    = (const float*)d_in[10];
    const float* sW     = (const float*)d_in[11];
    const float* sb     = (const float*)d_in[12];
    const float* Wih    = (const float*)d_in[13];
    const float* Whh    = (const float*)d_in[14];
    const float* bih    = (const float*)d_in[15];
    const float* bhh    = (const float*)d_in[16];
    const float* lW     = (const float*)d_in[17];
    const float* lb     = (const float*)d_in[18];

    float* out = (float*)d_out;
    char* ws = (char*)d_ws;
    int*    order = (int*)ws;                                       // 4 KB
    int*    rbase = (int*)(ws + 4096);                              // 4 KB
    __bf16* xcat  = (__bf16*)(ws + 8192);                           // 1.57 MB
    __bf16* wcat  = (__bf16*)(ws + 8192 + 1572864);                 // 1.57 MB
    __bf16* hnb   = (__bf16*)(ws + 8192 + 2 * 1572864);             // 0.5 MB
    __bf16* WT    = (__bf16*)(ws + 8192 + 2 * 1572864 + 524288);

    pre_kernel<<<K1_TOT, 1024, 0, stream>>>(ul, Wih, Whh, lW, order, rbase, wcat, WT);
    attn_kernel<<<B, 256, 0, stream>>>(hidden, io, ul, order, rbase, iW, ib, hW, hb,
                                       l1W, l1b, sW, sb, emb, out, xcat);
    xgemm_gate_kernel<<<dim3(16, 16), 256, 0, stream>>>(xcat, wcat, hidden, bih, bhh, out, hnb);
    out_mfma_kernel<<<NWG, 256, 0, stream>>>(hnb, WT, lb, out);
}

// Round 12
// 224.426 us; speedup vs baseline: 1.2046x; 1.2046x over previous
//
#include <hip/hip_runtime.h>
#include <math.h>

#define B 1024
#define M 15
#define H 256
#define E 256
#define V 30000
#define U 1000

typedef float  vf4    __attribute__((ext_vector_type(4)));
typedef __bf16 bf16x8 __attribute__((ext_vector_type(8)));
typedef float  f32x4  __attribute__((ext_vector_type(4)));

// output layout (flat f32 concat, reference return order)
#define O_OUT   0
#define O_HID   ((size_t)B*V)
#define O_EMB   (O_HID + (size_t)B*H)
#define O_GRU   (O_EMB + (size_t)B*E)
#define O_ATT   (O_GRU + (size_t)B*H)

#define GLDS(g, l) __builtin_amdgcn_global_load_lds( \
    (const __attribute__((address_space(1))) void*)(g), \
    (__attribute__((address_space(3))) void*)(l), 16, 0, 0)

union BF8 { __bf16 h[8]; bf16x8 v; };
union BF4 { __bf16 h[4]; unsigned long long u; };

// =============== kernel1: sort (bid 0) | transpose (1..500) | wcat (501..564) ===============
#define K1_TR   500
#define K1_WC   64
#define K1_TOT  (1 + K1_TR + K1_WC)

__global__ __launch_bounds__(1024) void pre_kernel(
    const int*   __restrict__ ul,
    const float* __restrict__ Wih,          // (3H,2E)
    const float* __restrict__ Whh,          // (3H,H)
    const float* __restrict__ lin_W,        // (H,V)
    int* __restrict__ order, int* __restrict__ rbase_g,
    __bf16* __restrict__ wcat,              // (1024,768), gate-group-reordered
    __bf16* __restrict__ WT)                // (V,H)
{
    __shared__ __align__(16) char smem[32640];
    const int bid = blockIdx.x;
    const int tid = threadIdx.x;

    if (bid == 0) {
        // ---------------- counting sort by user ----------------
        __shared__ int cnt[1024];
        __shared__ int base[1024];
        cnt[tid] = 0;
        __syncthreads();
        const int u = ul[tid];
        atomicAdd(&cnt[u], 1);
        __syncthreads();
        int c0 = cnt[tid];
        int v  = c0;
        for (int off = 1; off < 1024; off <<= 1) {
            int add = (tid >= off) ? cnt[tid - off] : 0;
            __syncthreads();
            v += add;
            cnt[tid] = v;
            __syncthreads();
        }
        base[tid]    = v - c0;
        rbase_g[tid] = v - c0;
        __syncthreads();
        int pos = atomicAdd(&base[u], 1);
        order[pos] = tid;
        return;
    }

    if (bid <= K1_TR) {
        // ---------------- transpose: lin_W (H,V) f32 -> WT (V,H) bf16 ----------------
        const int t   = bid - 1;
        const int v0  = (t % 125) * 240;
        const int k0  = (t / 125) * 64;
        const int lane = tid & 63, kq = tid >> 6;   // kq 0..15
        __bf16* T = (__bf16*)smem;                  // 240*68 bf16 = 32640 B

        if (lane < 60) {
            int kr = kq * 4;
            vf4 f0 = *(const vf4*)&lin_W[(size_t)(k0 + kr + 0) * V + v0 + lane * 4];
            vf4 f1 = *(const vf4*)&lin_W[(size_t)(k0 + kr + 1) * V + v0 + lane * 4];
            vf4 f2 = *(const vf4*)&lin_W[(size_t)(k0 + kr + 2) * V + v0 + lane * 4];
            vf4 f3 = *(const vf4*)&lin_W[(size_t)(k0 + kr + 3) * V + v0 + lane * 4];
            #pragma unroll
            for (int j = 0; j < 4; ++j) {
                BF4 pk;
                pk.h[0] = (__bf16)f0[j];
                pk.h[1] = (__bf16)f1[j];
                pk.h[2] = (__bf16)f2[j];
                pk.h[3] = (__bf16)f3[j];
                int v = lane * 4 + j;
                *(unsigned long long*)&T[v * 68 + kr] = pk.u;
            }
        }
        __syncthreads();
        #pragma unroll
        for (int r = 0; r < 4; ++r) {
            int L = r * 1024 + tid;
            int v = L >> 4, c = L & 15;
            if (v < 240)
                __builtin_nontemporal_store(
                    *(const unsigned long long*)&T[v * 68 + c * 4],
                    (unsigned long long*)&WT[(size_t)(v0 + v) * H + k0 + c * 4]);
        }
        return;
    }

    // ---------------- wcat (gate-group column order) ----------------
    {
        const int wb   = bid - 1 - K1_TR;
        const int lane = tid & 63;
        const int n    = wb * 16 + (tid >> 6);
        const int r    = (n >> 2) + ((n & 3) << 8);
        #pragma unroll
        for (int i = 0; i < 3; ++i) {
            int k = i * 256 + lane * 4;
            vf4 v = {0.f, 0.f, 0.f, 0.f};
            if (r < 512) {
                v = (k < 512) ? *(const vf4*)&Wih[(size_t)r * 512 + k]
                              : *(const vf4*)&Whh[(size_t)r * 256 + (k - 512)];
            } else if (r < 768) {
                if (k < 512) v = *(const vf4*)&Wih[(size_t)r * 512 + k];
            } else {
                if (k >= 512) v = *(const vf4*)&Whh[(size_t)(r - 256) * 256 + (k - 512)];
            }
            BF4 p;
            p.h[0]=(__bf16)v[0]; p.h[1]=(__bf16)v[1]; p.h[2]=(__bf16)v[2]; p.h[3]=(__bf16)v[3];
            *(unsigned long long*)&wcat[(size_t)n * 768 + k] = p.u;
        }
    }
}

// ---------------- Stage A: per-user attention (MFMA, reg-B, paired) ----------------
__global__ __launch_bounds__(256, 3) void attn_kernel(
    const float* __restrict__ hidden,       // (1,B,H)
    const float* __restrict__ inter_output, // (B,M,H)
    const int*   __restrict__ user_list,    // (B,)
    const int*   __restrict__ order,        // (B,)
    const int*   __restrict__ rbase,        // (1024,)
    const float* __restrict__ inter_W,      // (U,H,H)
    const float* __restrict__ inter_b,      // (U,H)
    const float* __restrict__ hidden_W,     // (U,H,H)
    const float* __restrict__ hidden_b,     // (U,H)
    const float* __restrict__ lt1_W,        // (U,2H,H)
    const float* __restrict__ lt1_b,        // (U,H)
    const float* __restrict__ scale_W,      // (U,H)
    const float* __restrict__ scale_b,      // (U,)
    const float* __restrict__ emb,          // (B,1,E)
    float* __restrict__ out,
    __bf16* __restrict__ xcat)              // (B,768)
{
    __shared__ __align__(16) char smem[34432];
    const int bid = blockIdx.x;
    const int tid = threadIdx.x;

    const int s   = ((bid & 7) << 7) + (bid >> 3);  // XCD chunk swizzle
    const int b0  = order[s];
    const int u   = user_list[b0];

    // cvt_xh for this block's sample (all 1024 blocks)
    {
        float ev = emb[(size_t)b0 * E + tid];
        float hv = hidden[(size_t)b0 * H + tid];
        xcat[(size_t)b0 * 768 + tid]       = (__bf16)ev;
        xcat[(size_t)b0 * 768 + 512 + tid] = (__bf16)hv;
        __builtin_nontemporal_store(ev, &out[O_EMB + (size_t)b0 * E + tid]);
    }

    if ((s - rbase[u]) & 1) return;         // not a run head
    bool paired = false;
    int  b1 = b0;
    if (s + 1 < B) {
        int ob = order[s + 1];
        if (user_list[ob] == u) { paired = true; b1 = ob; }
    }

    const int lane = tid & 63;
    const int wave = tid >> 6;
    const int wn0  = wave * 64;

    __bf16* Abuf = (__bf16*)smem;                       // 32 KB
    __bf16* hta  = (__bf16*)(smem + 32768);             // 2*256 bf16 = 1 KB
    float*  red  = (float*)(smem + 32768 + 1024);       // 2*64 f32 = 512 B
    float*  e_lds= (float*)(smem + 32768 + 1024 + 512); // 2*16 f32 = 128 B

    // ---- phase 1: A = [io|0 ; 0|ht] for both samples ----
    {
        const int r    = tid >> 3;
        const int part = tid & 7;
        const int sm   = r >> 4;
        const int mr   = r & 15;
        const int bs   = sm ? b1 : b0;
        const bool zr  = (sm == 1) && !paired;
        #pragma unroll
        for (int it = 0; it < 8; ++it) {
            int c = part + it * 8;
            int k = c * 8;
            BF8 p;
            #pragma unroll
            for (int j = 0; j < 8; ++j) p.h[j] = (__bf16)0.f;
            if (!zr) {
                if (mr < 15 && k < 256) {
                    vf4 f0 = *(const vf4*)&inter_output[(size_t)bs * M * H + mr * H + k];
                    vf4 f1 = *(const vf4*)&inter_output[(size_t)bs * M * H + mr * H + k + 4];
                    p.h[0]=(__bf16)f0[0]; p.h[1]=(__bf16)f0[1]; p.h[2]=(__bf16)f0[2]; p.h[3]=(__bf16)f0[3];
                    p.h[4]=(__bf16)f1[0]; p.h[5]=(__bf16)f1[1]; p.h[6]=(__bf16)f1[2]; p.h[7]=(__bf16)f1[3];
                } else if (mr == 15 && k >= 256) {
                    vf4 f0 = *(const vf4*)&hidden[(size_t)bs * H + (k - 256)];
                    vf4 f1 = *(const vf4*)&hidden[(size_t)bs * H + (k - 256) + 4];
                    p.h[0]=(__bf16)f0[0]; p.h[1]=(__bf16)f0[1]; p.h[2]=(__bf16)f0[2]; p.h[3]=(__bf16)f0[3];
                    p.h[4]=(__bf16)f1[0]; p.h[5]=(__bf16)f1[1]; p.h[6]=(__bf16)f1[2]; p.h[7]=(__bf16)f1[3];
                }
            }
            *(bf16x8*)&Abuf[r * 512 + (c ^ (r & 7)) * 8] = p.v;
        }
    }
    __syncthreads();

    const float* Wi_base  = inter_W  + (size_t)u * H * H;
    const float* Wh_base  = hidden_W + (size_t)u * H * H;
    const float* lt1_base = lt1_W    + (size_t)u * 2 * H * H;

    const int ocol = wn0 + (lane & 15);
    const int krow = (lane >> 4) * 8;

    f32x4 acc1[2][4];
    #pragma unroll
    for (int mf = 0; mf < 2; ++mf)
        #pragma unroll
        for (int nf = 0; nf < 4; ++nf) { f32x4 z = {0.f,0.f,0.f,0.f}; acc1[mf][nf] = z; }

    // ================= GEMM 1 =================
    #pragma unroll 2
    for (int ks = 0; ks < 16; ++ks) {
        const float* Bp = ((ks < 8) ? (Wi_base + (size_t)(ks * 32) * H)
                                    : (Wh_base + (size_t)((ks - 8) * 32) * H))
                          + (size_t)krow * H + ocol;
        float t[4][8];
        #pragma unroll
        for (int j = 0; j < 8; ++j)
            #pragma unroll
            for (int nf = 0; nf < 4; ++nf)
                t[nf][j] = Bp[(size_t)j * H + nf * 16];
        bf16x8 bfr[4];
        #pragma unroll
        for (int nf = 0; nf < 4; ++nf) {
            BF8 pk;
            #pragma unroll
            for (int j = 0; j < 8; ++j) pk.h[j] = (__bf16)t[nf][j];
            bfr[nf] = pk.v;
        }
        int sca = ((ks * 4 + (lane >> 4)) ^ (lane & 7)) * 8;
        bf16x8 a0 = *(const bf16x8*)&Abuf[(lane & 15) * 512 + sca];
        #pragma unroll
        for (int nf = 0; nf < 4; ++nf)
            acc1[0][nf] = __builtin_amdgcn_mfma_f32_16x16x32_bf16(a0, bfr[nf], acc1[0][nf], 0, 0, 0);
        if (paired) {
            bf16x8 a1 = *(const bf16x8*)&Abuf[(16 + (lane & 15)) * 512 + sca];
            #pragma unroll
            for (int nf = 0; nf < 4; ++nf)
                acc1[1][nf] = __builtin_amdgcn_mfma_f32_16x16x32_bf16(a1, bfr[nf], acc1[1][nf], 0, 0, 0);
        }
    }
    __syncthreads();

    // ---- extract ht_a + hidden_b ; io_a+bi into Abuf k>=256 ----
    if ((lane >> 4) == 3) {
        #pragma unroll
        for (int nf = 0; nf < 4; ++nf) {
            int o = wn0 + nf * 16 + (lane & 15);
            float hb = hidden_b[(size_t)u * H + o];
            hta[o]       = (__bf16)(acc1[0][nf][3] + hb);
            hta[256 + o] = (__bf16)(acc1[1][nf][3] + hb);
        }
    }
    #pragma unroll
    for (int mf = 0; mf < 2; ++mf) {
        #pragma unroll
        for (int nf = 0; nf < 4; ++nf) {
            int o  = wn0 + nf * 16 + (lane & 15);
            float bi = inter_b[(size_t)u * H + o];
            int k  = 256 + o;
            #pragma unroll
            for (int j = 0; j < 4; ++j) {
                int r  = mf * 16 + (lane >> 4) * 4 + j;
                Abuf[r * 512 + ((k >> 3) ^ (r & 7)) * 8 + (k & 7)] = (__bf16)(acc1[mf][nf][j] + bi);
            }
        }
    }
    __syncthreads();

    // ---- phase 2 low-K: hta broadcast ----
    {
        const int r    = tid >> 3;
        const int part = tid & 7;
        const int sm   = r >> 4;
        #pragma unroll
        for (int it = 0; it < 4; ++it) {
            int c = part + it * 8;
            bf16x8 hv = *(const bf16x8*)&hta[sm * 256 + c * 8];
            *(bf16x8*)&Abuf[r * 512 + (c ^ (r & 7)) * 8] = hv;
        }
    }
    __syncthreads();

    f32x4 acc2[2][4];
    #pragma unroll
    for (int mf = 0; mf < 2; ++mf)
        #pragma unroll
        for (int nf = 0; nf < 4; ++nf) { f32x4 z = {0.f,0.f,0.f,0.f}; acc2[mf][nf] = z; }

    // ================= GEMM 2 =================
    #pragma unroll 2
    for (int ks = 0; ks < 16; ++ks) {
        const float* Bp = lt1_base + (size_t)(ks * 32) * H + (size_t)krow * H + ocol;
        float t[4][8];
        #pragma unroll
        for (int j = 0; j < 8; ++j)
            #pragma unroll
            for (int nf = 0; nf < 4; ++nf)
                t[nf][j] = Bp[(size_t)j * H + nf * 16];
        bf16x8 bfr[4];
        #pragma unroll
        for (int nf = 0; nf < 4; ++nf) {
            BF8 pk;
            #pragma unroll
            for (int j = 0; j < 8; ++j) pk.h[j] = (__bf16)t[nf][j];
            bfr[nf] = pk.v;
        }
        int sca = ((ks * 4 + (lane >> 4)) ^ (lane & 7)) * 8;
        bf16x8 a0 = *(const bf16x8*)&Abuf[(lane & 15) * 512 + sca];
        #pragma unroll
        for (int nf = 0; nf < 4; ++nf)
            acc2[0][nf] = __builtin_amdgcn_mfma_f32_16x16x32_bf16(a0, bfr[nf], acc2[0][nf], 0, 0, 0);
        if (paired) {
            bf16x8 a1 = *(const bf16x8*)&Abuf[(16 + (lane & 15)) * 512 + sca];
            #pragma unroll
            for (int nf = 0; nf < 4; ++nf)
                acc2[1][nf] = __builtin_amdgcn_mfma_f32_16x16x32_bf16(a1, bfr[nf], acc2[1][nf], 0, 0, 0);
        }
    }

    // ---- energies ----
    float p0[4] = {0.f,0.f,0.f,0.f};
    float p1[4] = {0.f,0.f,0.f,0.f};
    #pragma unroll
    for (int nf = 0; nf < 4; ++nf) {
        int o = wn0 + nf * 16 + (lane & 15);
        float l1b = lt1_b[(size_t)u * H + o];
        float sw  = scale_W[(size_t)u * H + o];
        #pragma unroll
        for (int j = 0; j < 4; ++j)
            p0[j] += tanhf(acc2[0][nf][j] + l1b) * sw;
        if (paired)
            #pragma unroll
            for (int j = 0; j < 4; ++j)
                p1[j] += tanhf(acc2[1][nf][j] + l1b) * sw;
    }
    #pragma unroll
    for (int j = 0; j < 4; ++j) {
        float v = p0[j];
        v += __shfl_xor(v, 1, 64); v += __shfl_xor(v, 2, 64);
        v += __shfl_xor(v, 4, 64); v += __shfl_xor(v, 8, 64);
        if ((lane & 15) == 0) red[0 * 64 + wave * 16 + (lane >> 4) * 4 + j] = v;
        float w = p1[j];
        w += __shfl_xor(w, 1, 64); w += __shfl_xor(w, 2, 64);
        w += __shfl_xor(w, 4, 64); w += __shfl_xor(w, 8, 64);
        if ((lane & 15) == 0) red[1 * 64 + wave * 16 + (lane >> 4) * 4 + j] = w;
    }
    __syncthreads();
    if (tid < 32) {
        int sm = tid >> 4, mm = tid & 15;
        e_lds[sm * 16 + mm] = red[sm * 64 + mm] + red[sm * 64 + 16 + mm]
                            + red[sm * 64 + 32 + mm] + red[sm * 64 + 48 + mm]
                            + scale_b[u];
    }
    __syncthreads();

    const int nsm = paired ? 2 : 1;
    for (int sm = 0; sm < nsm; ++sm) {
        const int bs = sm ? b1 : b0;
        float mx = -1e30f;
        #pragma unroll
        for (int m = 0; m < M; ++m) mx = fmaxf(mx, e_lds[sm * 16 + m]);
        float sum = 0.f;
        float aw[M];
        #pragma unroll
        for (int m = 0; m < M; ++m) { aw[m] = expf(e_lds[sm * 16 + m] - mx); sum += aw[m]; }
        float inv = 1.f / sum;
        if (tid < M)
            __builtin_nontemporal_store(aw[tid] * inv, &out[O_ATT + (size_t)bs * M + tid]);
        float ctx = 0.f;
        #pragma unroll
        for (int m = 0; m < M; ++m)
            ctx += aw[m] * inter_output[(size_t)bs * M * H + m * H + tid];
        xcat[(size_t)bs * 768 + 256 + tid] = (__bf16)(ctx * inv);
    }
}

// ---- fused GRU GEMM + gate: gates tile in LDS, hn written directly ----
__global__ __launch_bounds__(256) void xgemm_gate_kernel(
    const __bf16* __restrict__ xcat, const __bf16* __restrict__ wcat,
    const float* __restrict__ hidden,
    const float* __restrict__ bih, const float* __restrict__ bhh,
    float* __restrict__ out, __bf16* __restrict__ hnb)
{
    const int n0   = blockIdx.x * 64;
    const int m0   = blockIdx.y * 64;
    const int tid  = threadIdx.x;
    const int wave = tid >> 6, lane = tid & 63;
    const int wm   = wave >> 1, wn = wave & 1;

    __shared__ __align__(16) __bf16 Al[64 * 128];
    __shared__ __align__(16) __bf16 Bl[64 * 128];
    __shared__ __align__(16) float  Cs[64 * 68];

    f32x4 acc[2][2];
    #pragma unroll
    for (int mf = 0; mf < 2; ++mf)
        #pragma unroll
        for (int nf = 0; nf < 2; ++nf) { f32x4 z = {0.f,0.f,0.f,0.f}; acc[mf][nf] = z; }

    for (int ks = 0; ks < 6; ++ks) {
        #pragma unroll
        for (int r = 0; r < 4; ++r) {
            int L = r * 256 + tid;
            int row = L >> 4, c = L & 15;
            int sc = c ^ (row & 7);
            GLDS(xcat + (size_t)(m0 + row) * 768 + ks * 128 + sc * 8, &Al[(size_t)L * 8]);
        }
        #pragma unroll
        for (int r = 0; r < 4; ++r) {
            int L = r * 256 + tid;
            int row = L >> 4, c = L & 15;
            int sc = c ^ (row & 7);
            GLDS(wcat + (size_t)(n0 + row) * 768 + ks * 128 + sc * 8, &Bl[(size_t)L * 8]);
        }
        __syncthreads();
        #pragma unroll
        for (int kk = 0; kk < 4; ++kk) {
            bf16x8 af[2];
            #pragma unroll
            for (int mf = 0; mf < 2; ++mf) {
                int row = wm * 32 + mf * 16 + (lane & 15);
                int c   = kk * 4 + (lane >> 4);
                af[mf] = *(const bf16x8*)&Al[row * 128 + (c ^ (row & 7)) * 8];
            }
            bf16x8 bfr[2];
            #pragma unroll
            for (int nf = 0; nf < 2; ++nf) {
                int col = wn * 32 + nf * 16 + (lane & 15);
                int c   = kk * 4 + (lane >> 4);
                bfr[nf] = *(const bf16x8*)&Bl[col * 128 + (c ^ (col & 7)) * 8];
            }
            #pragma unroll
            for (int mf = 0; mf < 2; ++mf)
                #pragma unroll
                for (int nf = 0; nf < 2; ++nf)
                    acc[mf][nf] = __builtin_amdgcn_mfma_f32_16x16x32_bf16(
                        af[mf], bfr[nf], acc[mf][nf], 0, 0, 0);
        }
        __syncthreads();
    }

    #pragma unroll
    for (int nf = 0; nf < 2; ++nf) {
        int lc = wn * 32 + nf * 16 + (lane & 15);
        #pragma unroll
        for (int mf = 0; mf < 2; ++mf) {
            int lr = wm * 32 + mf * 16 + (lane >> 4) * 4;
            f32x4 a = acc[mf][nf];
            #pragma unroll
            for (int j = 0; j < 4; ++j)
                Cs[(lr + j) * 68 + lc] = a[j];
        }
    }
    __syncthreads();

    #pragma unroll
    for (int k = 0; k < 4; ++k) {
        int idx = k * 256 + tid;
        int r = idx >> 4, g = idx & 15;
        f32x4 c = *(const f32x4*)&Cs[r * 68 + g * 4];
        int b = m0 + r;
        int j = (n0 >> 2) + g;
        float rs  = c[0] + bih[j]       + bhh[j];
        float zs  = c[1] + bih[256 + j] + bhh[256 + j];
        float gin = c[2] + bih[512 + j];
        float ghn = c[3] + bhh[512 + j];
        float h   = hidden[(size_t)b * H + j];
        float r_  = 1.f / (1.f + expf(-rs));
        float z_  = 1.f / (1.f + expf(-zs));
        float n_  = tanhf(gin + r_ * ghn);
        float hn  = (1.f - z_) * n_ + z_ * h;
        __builtin_nontemporal_store(hn, &out[O_HID + (size_t)b * H + j]);
        __builtin_nontemporal_store(hn, &out[O_GRU + (size_t)b * H + j]);
        hnb[(size_t)b * H + j] = (__bf16)hn;
    }
}

// -------- Stage C (MFMA): out = hnew(bf16) @ WT^T + lin_b --------
// (round-10 version: LDS-staged operands via global_load_lds, GBN=128, 3 blocks/CU)
#define GBM 64
#define GBN 128
#define GBK 64
#define NTM 16
#define NTN 235
#define NWG (NTN * NTM)
__global__ __launch_bounds__(256, 3) void out_mfma_kernel(
    const __bf16* __restrict__ hnb,
    const __bf16* __restrict__ WT,
    const float* __restrict__ lin_b,
    float* __restrict__ out)
{
    const int L  = blockIdx.x;
    const int s  = (L & 7) * (NWG / 8) + (L >> 3);
    const int nt = s >> 4, mt = s & 15;
    const int n0 = nt * GBN;
    const int m0 = mt * GBM;
    const int tid  = threadIdx.x;
    const int wave = tid >> 6, lane = tid & 63;

    __shared__ __align__(16) char gsm[GBM * H * 2 + GBN * GBK * 2];  // 48 KB
    __bf16* Al = (__bf16*)gsm;
    __bf16* Bl = (__bf16*)(gsm + GBM * H * 2);

    #pragma unroll
    for (int r = 0; r < 8; ++r) {
        int Li = r * 256 + tid;
        int m = Li >> 5;
        int c = Li & 31;
        int sc = c ^ (m & 7);
        GLDS(hnb + (size_t)(m0 + m) * H + sc * 8, &Al[(size_t)Li * 8]);
    }

    f32x4 acc[4][2];
    #pragma unroll
    for (int mf = 0; mf < 4; ++mf)
        #pragma unroll
        for (int nf = 0; nf < 2; ++nf) {
            f32x4 z = {0.f, 0.f, 0.f, 0.f};
            acc[mf][nf] = z;
        }

    const int wn0 = wave * 32;

    for (int ks = 0; ks < 4; ++ks) {
        #pragma unroll
        for (int r = 0; r < 4; ++r) {
            int Li = r * 256 + tid;
            int n = Li >> 3;
            int c = Li & 7;
            int sc = c ^ (n & 7);
            int nn = n0 + n; if (nn >= V) nn = V - 1;
            GLDS(WT + (size_t)nn * H + ks * GBK + sc * 8, &Bl[(size_t)Li * 8]);
        }
        __syncthreads();

        #pragma unroll
        for (int kk = 0; kk < 2; ++kk) {
            bf16x8 af[4];
            #pragma unroll
            for (int mf = 0; mf < 4; ++mf) {
                int row = mf * 16 + (lane & 15);
                int c   = ks * 8 + kk * 4 + (lane >> 4);
                int cs  = c ^ (row & 7);
                af[mf] = *(const bf16x8*)&Al[row * H + cs * 8];
            }
            bf16x8 bfr[2];
            #pragma unroll
            for (int nf = 0; nf < 2; ++nf) {
                int col = wn0 + nf * 16 + (lane & 15);
                int c   = kk * 4 + (lane >> 4);
                int cs  = c ^ (col & 7);
                bfr[nf] = *(const bf16x8*)&Bl[col * GBK + cs * 8];
            }
            #pragma unroll
            for (int mf = 0; mf < 4; ++mf)
                #pragma unroll
                for (int nf = 0; nf < 2; ++nf)
                    acc[mf][nf] = __builtin_amdgcn_mfma_f32_16x16x32_bf16(
                        af[mf], bfr[nf], acc[mf][nf], 0, 0, 0);
        }
        __syncthreads();
    }

    // ---- epilogue: stage C tile (64x128 f32 = 32 KB) in LDS, coalesced nt row writes ----
    float* Cs = (float*)gsm;
    #pragma unroll
    for (int nf = 0; nf < 2; ++nf) {
        int col = wn0 + nf * 16 + (lane & 15);
        #pragma unroll
        for (int mf = 0; mf < 4; ++mf) {
            #pragma unroll
            for (int j = 0; j < 4; ++j)
                Cs[(mf * 16 + (lane >> 4) * 4 + j) * 128 + col] = acc[mf][nf][j];
        }
    }
    __syncthreads();

    const int c4 = tid & 31;
    const bool nok = (n0 + c4 * 4 + 3 < V);
    f32x4 lb = {0.f, 0.f, 0.f, 0.f};
    if (nok) lb = *(const f32x4*)&lin_b[n0 + c4 * 4];
    #pragma unroll
    for (int it = 0; it < 8; ++it) {
        int idx = it * 256 + tid;
        int r = idx >> 5;
        f32x4 c = *(const f32x4*)&Cs[r * 128 + c4 * 4];
        c += lb;
        if (nok)
            __builtin_nontemporal_store(c, (f32x4*)&out[(size_t)(m0 + r) * V + n0 + c4 * 4]);
    }
}

extern "C" void kernel_launch(void* const* d_in, const int* in_sizes, int n_in,
                              void* d_out, int out_size, void* d_ws, size_t ws_size,
                              hipStream_t stream) {
    const float* emb    = (const float*)d_in[1];
    const float* hidden = (const float*)d_in[2];
    const float* io     = (const float*)d_in[3];
    const int*   ul     = (const int*)  d_in[4];
    const float* iW     = (const float*)d_in[5];
    const float* ib     = (const float*)d_in[6];
    const float* hW     = (const float*)d_in[7];
    const float* hb     = (const float*)d_in[8];
    const float* l1W    = (const float*)d_in[9];
    const float* l1b    = (const float*)d_in[10];
    const float* sW     = (const float*)d_in[11];
    const float* sb     = (const float*)d_in[12];
    const float* Wih    = (const float*)d_in[13];
    const float* Whh    = (const float*)d_in[14];
    const float* bih    = (const float*)d_in[15];
    const float* bhh    = (const float*)d_in[16];
    const float* lW     = (const float*)d_in[17];
    const float* lb     = (const float*)d_in[18];

    float* out = (float*)d_out;
    char* ws = (char*)d_ws;
    int*    order = (int*)ws;                                       // 4 KB
    int*    rbase = (int*)(ws + 4096);                              // 4 KB
    __bf16* xcat  = (__bf16*)(ws + 8192);                           // 1.57 MB
    __bf16* wcat  = (__bf16*)(ws + 8192 + 1572864);                 // 1.57 MB
    __bf16* hnb   = (__bf16*)(ws + 8192 + 2 * 1572864);             // 0.5 MB
    __bf16* WT    = (__bf16*)(ws + 8192 + 2 * 1572864 + 524288);

    pre_kernel<<<K1_TOT, 1024, 0, stream>>>(ul, Wih, Whh, lW, order, rbase, wcat, WT);
    attn_kernel<<<B, 256, 0, stream>>>(hidden, io, ul, order, rbase, iW, ib, hW, hb,
                                       l1W, l1b, sW, sb, emb, out, xcat);
    xgemm_gate_kernel<<<dim3(16, 16), 256, 0, stream>>>(xcat, wcat, hidden, bih, bhh, out, hnb);
    out_mfma_kernel<<<NWG, 256, 0, stream>>>(hnb, WT, lb, out);
}